// Round 9
// baseline (315.573 us; speedup 1.0000x reference)
//
#include <hip/hip_runtime.h>
#include <hip/hip_bf16.h>
#include <cstdint>
#include <cstddef>

#define N_NODES 8192
#define NE      131072
#define NR      4
#define NC      1280   // [root | W0..W3] * 256
#define SLOTS   96

typedef __attribute__((ext_vector_type(8))) short bf16x8;
typedef __attribute__((ext_vector_type(4))) float f32x4;

__device__ __forceinline__ float sigmoidf_(float x) {
  return 1.0f / (1.0f + __expf(-x));
}

__device__ __forceinline__ ushort f2b(float v) {
  __hip_bfloat16 h = __float2bfloat16(v);
  return *(ushort*)&h;
}
__device__ __forceinline__ float b2f(ushort u) {
  __hip_bfloat16 h = *(__hip_bfloat16*)&u;
  return __bfloat162float(h);
}
__device__ __forceinline__ void split2(float v, ushort& hi, ushort& lo) {
  hi = f2b(v);
  lo = f2b(v - b2f(hi));
}
__device__ __forceinline__ bf16x8 pack8(float4 a, float4 b) {
  bf16x8 r;
  r[0] = (short)f2b(a.x); r[1] = (short)f2b(a.y); r[2] = (short)f2b(a.z); r[3] = (short)f2b(a.w);
  r[4] = (short)f2b(b.x); r[5] = (short)f2b(b.y); r[6] = (short)f2b(b.z); r[7] = (short)f2b(b.w);
  return r;
}

// ====== fused: adjacency fill (blocks 0..511) + weight pack (blocks 512..711) ======
__global__ __launch_bounds__(256) void k_fill_pack(
    const int* __restrict__ src, const int* __restrict__ dst, const int* __restrict__ et,
    int* __restrict__ cnt, int* __restrict__ slots,
    int* __restrict__ cnt2, int* __restrict__ slots2,
    const float* __restrict__ r1, const float* __restrict__ W1,
    const float* __restrict__ r2, const float* __restrict__ W2,
    ushort* __restrict__ B1t, ushort* __restrict__ B2thi, ushort* __restrict__ B2tlo) {
  __shared__ ushort sh[64][66];
  __shared__ ushort sl[64][66];
  if (blockIdx.x < 512) {
    int e = blockIdx.x * 256 + threadIdx.x;      // 512*256 == NE exactly
    int d = dst[e], s = src[e];
    int pos = atomicAdd(&cnt[d], 1);
    if (pos < SLOTS) slots[(size_t)d * SLOTS + pos] = (s << 2) | et[e];
    int pos2 = atomicAdd(&cnt2[s], 1);
    if (pos2 < SLOTS) slots2[(size_t)s * SLOTS + pos2] = d;
    return;
  }
  int b = blockIdx.x - 512;
  int layer, K, kt, nt, seg;
  const float *srcR, *srcW;
  if (b < 120) { layer = 1; K = 384; int t = b;       seg = t / 24; t %= 24; kt = t / 4; nt = t % 4; srcR = r1; srcW = W1; }
  else         { layer = 2; K = 256; int t = b - 120; seg = t / 16; t %= 16; kt = t / 4; nt = t % 4; srcR = r2; srcW = W2; }
  int k0 = kt * 64, n0 = nt * 64;
  int tid = threadIdx.x;
#pragma unroll
  for (int it = 0; it < 16; ++it) {
    int idx = it * 256 + tid;
    int kl = idx >> 6, nl = idx & 63;
    int kg = k0 + kl, c = n0 + nl;
    float v = (seg == 0) ? srcR[(size_t)kg * 256 + c]
                         : srcW[((size_t)(seg - 1) * K + kg) * 256 + c];
    ushort h, l; split2(v, h, l);
    sh[kl][nl] = h;
    sl[kl][nl] = l;
  }
  __syncthreads();
#pragma unroll
  for (int it = 0; it < 16; ++it) {
    int idx = it * 256 + tid;
    int nl = idx >> 6, kl = idx & 63;
    size_t o = (size_t)(seg * 256 + n0 + nl) * K + k0 + kl;
    if (layer == 1) {
      B1t[o] = sh[kl][nl];
    } else {
      B2thi[o] = sh[kl][nl];
      B2tlo[o] = sl[kl][nl];
    }
  }
}

// ======== layer-1 GEMM with fused embedding gather (r8-exact) ========
__global__ __launch_bounds__(256) void k_gemm1e(
    const int* __restrict__ x,
    const float* __restrict__ e0, const float* __restrict__ e1,
    const float* __restrict__ e2, const float* __restrict__ e3,
    const float* __restrict__ e4, const float* __restrict__ e5,
    const ushort* __restrict__ Bhi, ushort* __restrict__ Cb) {
  constexpr int K = 384;
  __shared__ ushort BsH[128 * 128];
  const int tid = threadIdx.x;
  const int w = tid >> 6, l = tid & 63;
  const int lrow = l & 15, lk8 = (l >> 4) * 8;
  const int brow = blockIdx.y * 128, bcol = blockIdx.x * 128;
  const int r0 = brow + w * 32 + lrow, r1i = r0 + 16;

  int idx0[6], idx1[6];
#pragma unroll
  for (int j = 0; j < 3; ++j) {
    int2 a = *(const int2*)(x + (size_t)r0 * 6 + j * 2);
    idx0[j * 2] = a.x; idx0[j * 2 + 1] = a.y;
    int2 b = *(const int2*)(x + (size_t)r1i * 6 + j * 2);
    idx1[j * 2] = b.x; idx1[j * 2 + 1] = b.y;
  }
  const float* tabs[6] = {e0, e1, e2, e3, e4, e5};

  f32x4 acc[2][8] = {};
#pragma unroll
  for (int kc = 0; kc < K; kc += 128) {
    bf16x8 aH[4][2];
#pragma unroll
    for (int kk = 0; kk < 4; ++kk) {
      const int base = kc + kk * 32;
      const int ti = base >> 6;
      const int dd = (base & 63) + lk8;
      const float* t0 = tabs[ti] + (size_t)idx0[ti] * 64 + dd;
      const float* t1 = tabs[ti] + (size_t)idx1[ti] * 64 + dd;
      aH[kk][0] = pack8(*(const float4*)t0, *(const float4*)(t0 + 4));
      aH[kk][1] = pack8(*(const float4*)t1, *(const float4*)(t1 + 4));
    }
    if (kc) __syncthreads();
#pragma unroll
    for (int it = 0; it < 8; ++it) {
      int o = (it * 256 + tid) * 16;
      int row = o >> 8, sb = o & 255;
      int se = (sb ^ ((row & 7) << 4)) >> 1;
      size_t g = (size_t)(bcol + row) * K + kc + se;
      *(uint4*)((char*)BsH + o) = *(const uint4*)(Bhi + g);
    }
    __syncthreads();
#pragma unroll
    for (int kk = 0; kk < 4; ++kk) {
#pragma unroll
      for (int n = 0; n < 8; ++n) {
        int row_t = n * 16 + lrow;
        int addr = row_t * 256 + ((kk * 64 + (l >> 4) * 16) ^ ((row_t & 7) << 4));
        bf16x8 b_h = *(const bf16x8*)((const char*)BsH + addr);
        acc[0][n] = __builtin_amdgcn_mfma_f32_16x16x32_bf16(aH[kk][0], b_h, acc[0][n], 0, 0, 0);
        acc[1][n] = __builtin_amdgcn_mfma_f32_16x16x32_bf16(aH[kk][1], b_h, acc[1][n], 0, 0, 0);
      }
    }
  }
  const int crow = (l >> 4) * 4, ccol = l & 15;
#pragma unroll
  for (int m = 0; m < 2; ++m)
#pragma unroll
    for (int n = 0; n < 8; ++n) {
      int rloc = w * 32 + m * 16 + crow;
      int cloc = n * 16 + ccol;
#pragma unroll
      for (int r = 0; r < 4; ++r)
        Cb[(size_t)(brow + rloc + r) * NC + bcol + cloc] = f2b(acc[m][n][r]);
    }
}

// ============ unified MFMA GEMM (r7-exact): C(M,Nc) = A(M,K) @ B(Nc,K)^T ============
template<int SPLIT3, int ACT, int SYM, int OUT>
__global__ __launch_bounds__(256) void k_gemm2(
    const ushort* __restrict__ Ahi, const ushort* __restrict__ Alo,
    const ushort* __restrict__ Bhi, const ushort* __restrict__ Blo,
    void* __restrict__ Cv, int Nc, int K) {
  __shared__ ushort Bs[(SPLIT3 ? 2 : 1) * 128 * 128];
  ushort* BsH = Bs;
  ushort* BsL = Bs + 128 * 128;

  const int tid = threadIdx.x;
  const int w = tid >> 6, l = tid & 63;
  const int lrow = l & 15, lk8 = (l >> 4) * 8;

  int brow, bcol, p = 0, q = 0;
  if (SYM) {
    int b = blockIdx.x;
    q = (int)((sqrtf(8.f * (float)b + 1.f) - 1.f) * 0.5f);
    while ((q + 1) * (q + 2) / 2 <= b) ++q;
    while (q * (q + 1) / 2 > b) --q;
    p = b - q * (q + 1) / 2;          // p <= q
    brow = p * 128; bcol = q * 128;
  } else {
    brow = blockIdx.y * 128; bcol = blockIdx.x * 128;
  }

  f32x4 acc[2][8] = {};
  const size_t arow0 = (size_t)(brow + w * 32 + lrow) * K + lk8;
  const size_t arow1 = arow0 + (size_t)16 * K;

  for (int kc = 0; kc < K; kc += 128) {
    bf16x8 aH[4][2], aL[4][2];
#pragma unroll
    for (int kk = 0; kk < 4; ++kk) {
      aH[kk][0] = *(const bf16x8*)(Ahi + arow0 + kc + kk * 32);
      aH[kk][1] = *(const bf16x8*)(Ahi + arow1 + kc + kk * 32);
      if (SPLIT3) {
        aL[kk][0] = *(const bf16x8*)(Alo + arow0 + kc + kk * 32);
        aL[kk][1] = *(const bf16x8*)(Alo + arow1 + kc + kk * 32);
      }
    }
    if (kc) __syncthreads();
#pragma unroll
    for (int it = 0; it < 8; ++it) {
      int o = (it * 256 + tid) * 16;
      int row = o >> 8, sb = o & 255;
      int se = (sb ^ ((row & 7) << 4)) >> 1;
      size_t g = (size_t)(bcol + row) * K + kc + se;
      *(uint4*)((char*)BsH + o) = *(const uint4*)(Bhi + g);
      if (SPLIT3) *(uint4*)((char*)BsL + o) = *(const uint4*)(Blo + g);
    }
    __syncthreads();
#pragma unroll
    for (int kk = 0; kk < 4; ++kk) {
#pragma unroll
      for (int n = 0; n < 8; ++n) {
        int row_t = n * 16 + lrow;
        int addr = row_t * 256 + ((kk * 64 + (l >> 4) * 16) ^ ((row_t & 7) << 4));
        bf16x8 b_h = *(const bf16x8*)((const char*)BsH + addr);
        acc[0][n] = __builtin_amdgcn_mfma_f32_16x16x32_bf16(aH[kk][0], b_h, acc[0][n], 0, 0, 0);
        acc[1][n] = __builtin_amdgcn_mfma_f32_16x16x32_bf16(aH[kk][1], b_h, acc[1][n], 0, 0, 0);
        if (SPLIT3) {
          bf16x8 b_l = *(const bf16x8*)((const char*)BsL + addr);
          acc[0][n] = __builtin_amdgcn_mfma_f32_16x16x32_bf16(aL[kk][0], b_h, acc[0][n], 0, 0, 0);
          acc[1][n] = __builtin_amdgcn_mfma_f32_16x16x32_bf16(aL[kk][1], b_h, acc[1][n], 0, 0, 0);
          acc[0][n] = __builtin_amdgcn_mfma_f32_16x16x32_bf16(aH[kk][0], b_l, acc[0][n], 0, 0, 0);
          acc[1][n] = __builtin_amdgcn_mfma_f32_16x16x32_bf16(aH[kk][1], b_l, acc[1][n], 0, 0, 0);
        }
      }
    }
  }

  const int crow = (l >> 4) * 4, ccol = l & 15;
  float*  Cf = (float*)Cv;
  ushort* Cb = (ushort*)Cv;
  const int domirror = (SYM && p != q);
  if (SYM) { if (domirror) __syncthreads(); }   // Bs free for reuse as transpose buffer
  float* T = (float*)Bs;                        // 128x128 f32 (64 KB) when SPLIT3
#pragma unroll
  for (int m = 0; m < 2; ++m)
#pragma unroll
    for (int n = 0; n < 8; ++n) {
      float v[4];
#pragma unroll
      for (int r = 0; r < 4; ++r) {
        float t = acc[m][n][r];
        v[r] = ACT ? sigmoidf_(t) : t;
      }
      int rloc = w * 32 + m * 16 + crow;
      int cloc = n * 16 + ccol;
#pragma unroll
      for (int r = 0; r < 4; ++r) {
        if (OUT) Cb[(size_t)(brow + rloc + r) * Nc + bcol + cloc] = f2b(v[r]);
        else     Cf[(size_t)(brow + rloc + r) * Nc + bcol + cloc] = v[r];
      }
      if (SYM && p != q) {
        int s = (cloc & 7) << 2;                // XOR swizzle on col, 4-float granule
#pragma unroll
        for (int r = 0; r < 4; ++r) T[cloc * 128 + ((rloc + r) ^ s)] = v[r];
      }
    }
  if (SYM && p != q) {
    __syncthreads();
#pragma unroll
    for (int it = 0; it < 16; ++it) {
      int idx = it * 256 + tid;
      int rw = idx >> 5;                        // 0..127 mirror row
      int c4 = (idx & 31) * 4;                  // 0..124 col chunk
      int s = (rw & 7) << 2;
      float4 val = *(const float4*)&T[rw * 128 + (c4 ^ s)];
      *(float4*)(Cf + (size_t)(bcol + rw) * Nc + brow + c4) = val;
    }
  }
}

// ---------------- threefry (partitionable) -> normal ----------------
__device__ __forceinline__ float bits_to_normal(unsigned bits) {
  float f = __uint_as_float((bits >> 9) | 0x3f800000u) - 1.0f;  // [0,1)
  const float lo = -0.99999994f;  // nextafter(-1,0) f32
  float u = __fadd_rn(__fmul_rn(f, 2.0f), lo);
  u = fmaxf(lo, u);
  float w = -log1pf(-u * u);
  float p;
  if (w < 5.0f) {
    w = w - 2.5f;
    p = 2.81022636e-08f;
    p = fmaf(p, w, 3.43273939e-07f);
    p = fmaf(p, w, -3.5233877e-06f);
    p = fmaf(p, w, -4.39150654e-06f);
    p = fmaf(p, w, 0.00021858087f);
    p = fmaf(p, w, -0.00125372503f);
    p = fmaf(p, w, -0.00417768164f);
    p = fmaf(p, w, 0.246640727f);
    p = fmaf(p, w, 1.50140941f);
  } else {
    w = sqrtf(w) - 3.0f;
    p = -0.000200214257f;
    p = fmaf(p, w, 0.000100950558f);
    p = fmaf(p, w, 0.00134934322f);
    p = fmaf(p, w, -0.00367342844f);
    p = fmaf(p, w, 0.00573950773f);
    p = fmaf(p, w, -0.0076224613f);
    p = fmaf(p, w, 0.00943887047f);
    p = fmaf(p, w, 1.00167406f);
    p = fmaf(p, w, 2.83297682f);
  }
  return 1.41421356f * (p * u);   // sqrt(2) * erfinv(u)
}

__device__ __forceinline__ unsigned threefry_bits(unsigned j) {
  const unsigned ks0 = 0u, ks1 = 42u, ks2 = 0x1BD11BDAu ^ 0u ^ 42u;
  unsigned x0 = 0u + ks0;
  unsigned x1 = j + ks1;
#define RND(r) { x0 += x1; x1 = (x1 << r) | (x1 >> (32 - r)); x1 ^= x0; }
  RND(13) RND(15) RND(26) RND(6)  x0 += ks1; x1 += ks2 + 1u;
  RND(17) RND(29) RND(16) RND(24) x0 += ks2; x1 += ks0 + 2u;
  RND(13) RND(15) RND(26) RND(6)  x0 += ks0; x1 += ks1 + 3u;
  RND(17) RND(29) RND(16) RND(24) x0 += ks1; x1 += ks2 + 4u;
  RND(13) RND(15) RND(26) RND(6)  x0 += ks2; x1 += ks0 + 5u;
#undef RND
  return x0 ^ x1;
}

// ====== combine layer 1 (blocks 0..8191, r8-exact) + A-row generation (8192..16383) ======
__global__ __launch_bounds__(256) void k_combine1A(
    const ushort* __restrict__ hall, const float* __restrict__ bias,
    const int* __restrict__ cnt, const int* __restrict__ slots,
    ushort* __restrict__ h_hi, ushort* __restrict__ h_lo,
    const int* __restrict__ cnt2, const int* __restrict__ slots2,
    float* __restrict__ A) {
  __shared__ int sc[64];
  if (blockIdx.x >= N_NODES) {
    // ---- A row: per-thread 32-col span, bitmask -> branch-free float4 stores ----
    int n = blockIdx.x - N_NODES;
    int tid = threadIdx.x;
    int m = min(cnt2[n], SLOTS);
    const int* sl2 = slots2 + (size_t)n * SLOTS;
    unsigned mask = 0;
    for (int j = 0; j < m; ++j) {
      int d = sl2[j];                       // wave-uniform broadcast load
      if ((d >> 5) == tid) mask |= 1u << (d & 31);
    }
    float* rowp = A + (size_t)n * N_NODES + tid * 32;
#pragma unroll
    for (int w2 = 0; w2 < 8; ++w2) {
      float4 v;
      v.x = (mask >> (w2 * 4 + 0)) & 1 ? 1.0f : 0.0f;
      v.y = (mask >> (w2 * 4 + 1)) & 1 ? 1.0f : 0.0f;
      v.z = (mask >> (w2 * 4 + 2)) & 1 ? 1.0f : 0.0f;
      v.w = (mask >> (w2 * 4 + 3)) & 1 ? 1.0f : 0.0f;
      *(float4*)(rowp + w2 * 4) = v;
    }
    return;
  }
  int n = blockIdx.x, c = threadIdx.x;
  int end = min(cnt[n], SLOTS);
  const int* sl = slots + (size_t)n * SLOTS;
  float a0 = 0.f, a1 = 0.f, a2 = 0.f, a3 = 0.f;
  int c0 = 0, c1 = 0, c2 = 0, c3 = 0;
  for (int base = 0; base < end; base += 64) {
    int mcnt = min(64, end - base);
    if (c < 64 && base + c < end) sc[c] = sl[base + c];
    __syncthreads();
    int i = 0;
    for (; i + 4 <= mcnt; i += 4) {
      int p0 = sc[i], p1 = sc[i + 1], p2 = sc[i + 2], p3 = sc[i + 3];
      float v0 = b2f(hall[(size_t)(p0 >> 2) * NC + 256 + (size_t)(p0 & 3) * 256 + c]);
      float v1 = b2f(hall[(size_t)(p1 >> 2) * NC + 256 + (size_t)(p1 & 3) * 256 + c]);
      float v2 = b2f(hall[(size_t)(p2 >> 2) * NC + 256 + (size_t)(p2 & 3) * 256 + c]);
      float v3 = b2f(hall[(size_t)(p3 >> 2) * NC + 256 + (size_t)(p3 & 3) * 256 + c]);
      int r;
      r = p0 & 3; if (r == 0) { a0 += v0; ++c0; } else if (r == 1) { a1 += v0; ++c1; }
                  else if (r == 2) { a2 += v0; ++c2; } else { a3 += v0; ++c3; }
      r = p1 & 3; if (r == 0) { a0 += v1; ++c0; } else if (r == 1) { a1 += v1; ++c1; }
                  else if (r == 2) { a2 += v1; ++c2; } else { a3 += v1; ++c3; }
      r = p2 & 3; if (r == 0) { a0 += v2; ++c0; } else if (r == 1) { a1 += v2; ++c1; }
                  else if (r == 2) { a2 += v2; ++c2; } else { a3 += v2; ++c3; }
      r = p3 & 3; if (r == 0) { a0 += v3; ++c0; } else if (r == 1) { a1 += v3; ++c1; }
                  else if (r == 2) { a2 += v3; ++c2; } else { a3 += v3; ++c3; }
    }
    for (; i < mcnt; ++i) {
      int pp = sc[i];
      int r = pp & 3;
      float v = b2f(hall[(size_t)(pp >> 2) * NC + 256 + (size_t)r * 256 + c]);
      if (r == 0) { a0 += v; ++c0; } else if (r == 1) { a1 += v; ++c1; }
      else if (r == 2) { a2 += v; ++c2; } else { a3 += v; ++c3; }
    }
    __syncthreads();
  }
  float v = b2f(hall[(size_t)n * NC + c]) + bias[c]
          + a0 / (float)max(c0, 1) + a1 / (float)max(c1, 1)
          + a2 / (float)max(c2, 1) + a3 / (float)max(c3, 1);
  float sg = sigmoidf_(v);
  ushort h, l; split2(sg, h, l);
  h_hi[(size_t)n * 256 + c] = h;
  h_lo[(size_t)n * 256 + c] = l;
}

// -------- combine layer 2 (f32 hall, r8-exact) + fused reparametrize --------
__global__ __launch_bounds__(256) void k_combine2z(
    const float* __restrict__ hall, const float* __restrict__ bias,
    const int* __restrict__ cnt, const int* __restrict__ slots,
    float* __restrict__ muo, float* __restrict__ lvo,
    ushort* __restrict__ zhi, ushort* __restrict__ zlo) {
  __shared__ int sc[64];
  __shared__ float sv[256];
  int n = blockIdx.x, c = threadIdx.x;
  int end = min(cnt[n], SLOTS);
  const int* sl = slots + (size_t)n * SLOTS;
  float a0 = 0.f, a1 = 0.f, a2 = 0.f, a3 = 0.f;
  int c0 = 0, c1 = 0, c2 = 0, c3 = 0;
  for (int base = 0; base < end; base += 64) {
    int mcnt = min(64, end - base);
    if (c < 64 && base + c < end) sc[c] = sl[base + c];
    __syncthreads();
    int i = 0;
    for (; i + 4 <= mcnt; i += 4) {
      int p0 = sc[i], p1 = sc[i + 1], p2 = sc[i + 2], p3 = sc[i + 3];
      float v0 = hall[(size_t)(p0 >> 2) * NC + 256 + (size_t)(p0 & 3) * 256 + c];
      float v1 = hall[(size_t)(p1 >> 2) * NC + 256 + (size_t)(p1 & 3) * 256 + c];
      float v2 = hall[(size_t)(p2 >> 2) * NC + 256 + (size_t)(p2 & 3) * 256 + c];
      float v3 = hall[(size_t)(p3 >> 2) * NC + 256 + (size_t)(p3 & 3) * 256 + c];
      int r;
      r = p0 & 3; if (r == 0) { a0 += v0; ++c0; } else if (r == 1) { a1 += v0; ++c1; }
                  else if (r == 2) { a2 += v0; ++c2; } else { a3 += v0; ++c3; }
      r = p1 & 3; if (r == 0) { a0 += v1; ++c0; } else if (r == 1) { a1 += v1; ++c1; }
                  else if (r == 2) { a2 += v1; ++c2; } else { a3 += v1; ++c3; }
      r = p2 & 3; if (r == 0) { a0 += v2; ++c0; } else if (r == 1) { a1 += v2; ++c1; }
                  else if (r == 2) { a2 += v2; ++c2; } else { a3 += v2; ++c3; }
      r = p3 & 3; if (r == 0) { a0 += v3; ++c0; } else if (r == 1) { a1 += v3; ++c1; }
                  else if (r == 2) { a2 += v3; ++c2; } else { a3 += v3; ++c3; }
    }
    for (; i < mcnt; ++i) {
      int pp = sc[i];
      int r = pp & 3;
      float v = hall[(size_t)(pp >> 2) * NC + 256 + (size_t)r * 256 + c];
      if (r == 0) { a0 += v; ++c0; } else if (r == 1) { a1 += v; ++c1; }
      else if (r == 2) { a2 += v; ++c2; } else { a3 += v; ++c3; }
    }
    __syncthreads();
  }
  float v = hall[(size_t)n * NC + c] + bias[c]
          + a0 / (float)max(c0, 1) + a1 / (float)max(c1, 1)
          + a2 / (float)max(c2, 1) + a3 / (float)max(c3, 1);
  float sg = sigmoidf_(v);
  if (c < 128) muo[(size_t)n * 128 + c] = sg;
  else         lvo[(size_t)n * 128 + (c - 128)] = sg;
  sv[c] = sg;
  __syncthreads();
  if (c < 128) {
    unsigned j = (unsigned)n * 128u + (unsigned)c;
    float e = bits_to_normal(threefry_bits(j));
    float z = fmaf(e, __expf(0.5f * sv[c + 128]), sv[c]);
    ushort h, l; split2(z, h, l);
    zhi[j] = h; zlo[j] = l;
  }
}

extern "C" void kernel_launch(void* const* d_in, const int* in_sizes, int n_in,
                              void* d_out, int out_size, void* d_ws, size_t ws_size,
                              hipStream_t stream) {
  const int* x    = (const int*)d_in[0];
  const int* ei   = (const int*)d_in[1];
  const int* src  = ei;
  const int* dst  = ei + NE;
  const int* et   = (const int*)d_in[2];
  const float* e0 = (const float*)d_in[3];
  const float* e1 = (const float*)d_in[4];
  const float* e2 = (const float*)d_in[5];
  const float* e3 = (const float*)d_in[6];
  const float* e4 = (const float*)d_in[7];
  const float* e5 = (const float*)d_in[8];
  const float* W1 = (const float*)d_in[9];
  const float* r1 = (const float*)d_in[10];
  const float* b1 = (const float*)d_in[11];
  const float* W2 = (const float*)d_in[12];
  const float* r2 = (const float*)d_in[13];
  const float* b2 = (const float*)d_in[14];

  float* out  = (float*)d_out;
  float* A    = out;                                    // N*N
  float* Ahat = out + (size_t)N_NODES * N_NODES;        // N*N
  float* muo  = Ahat + (size_t)N_NODES * N_NODES;       // N*128
  float* lvo  = muo + (size_t)N_NODES * 128;            // N*128

  char* wp = (char*)d_ws;
  auto carve = [&](size_t bytes) { char* r = wp; wp += (bytes + 255) & ~(size_t)255; return r; };
  ushort* B1t    = (ushort*)carve((size_t)NC * 384 * 2);
  ushort* B2thi  = (ushort*)carve((size_t)NC * 256 * 2);
  ushort* B2tlo  = (ushort*)carve((size_t)NC * 256 * 2);
  float*  hall   = (float*)carve((size_t)8192 * NC * 4);  // f32 layer2; bf16 alias layer1
  ushort* hallb  = (ushort*)hall;
  ushort* h1hi   = (ushort*)carve((size_t)8192 * 256 * 2);
  ushort* h1lo   = (ushort*)carve((size_t)8192 * 256 * 2);
  ushort* zhi    = (ushort*)carve((size_t)8192 * 128 * 2);
  ushort* zlo    = (ushort*)carve((size_t)8192 * 128 * 2);
  int*    cnt    = (int*)carve((size_t)8192 * 4);
  int*    cnt2   = (int*)carve((size_t)8192 * 4);          // contiguous with cnt
  int*    slots  = (int*)carve((size_t)8192 * SLOTS * 4);
  int*    slots2 = (int*)carve((size_t)8192 * SLOTS * 4);

  // ---- adjacency (both keys) + weight pack in one launch ----
  hipMemsetAsync(cnt, 0, (size_t)2 * 8192 * 4, stream);
  k_fill_pack<<<712, 256, 0, stream>>>(src, dst, et, cnt, slots, cnt2, slots2,
                                       r1, W1, r2, W2, B1t, B2thi, B2tlo);

  // ---- layer 1 (embed-fused hi-only GEMM -> bf16 hall) ----
  k_gemm1e<<<dim3(NC / 128, 64), 256, 0, stream>>>(
      x, e0, e1, e2, e3, e4, e5, B1t, hallb);

  // ---- combine1 + A-row generation overlapped in one launch ----
  k_combine1A<<<2 * N_NODES, 256, 0, stream>>>(hallb, b1, cnt, slots, h1hi, h1lo,
                                               cnt2, slots2, A);

  // ---- layer 2 (split-3 GEMM, f32 hall) + fused reparametrize ----
  k_gemm2<1, 0, 0, 0><<<dim3(NC / 128, 64), 256, 0, stream>>>(
      h1hi, h1lo, B2thi, B2tlo, hall, NC, 256);
  k_combine2z<<<8192, 256, 0, stream>>>(hall, b2, cnt, slots, muo, lvo, zhi, zlo);

  // ---- A_hat = sigmoid(Z @ Z^T): sym triangle, LDS-transposed mirror (r7-exact) ----
  k_gemm2<1, 1, 1, 0><<<dim3(64 * 65 / 2), 256, 0, stream>>>(
      zhi, zlo, zhi, zlo, Ahat, N_NODES, 128);
}

// Round 10
// 291.019 us; speedup vs baseline: 1.0844x; 1.0844x over previous
//
#include <hip/hip_runtime.h>
#include <hip/hip_bf16.h>
#include <cstdint>
#include <cstddef>

#define N_NODES 8192
#define NE      131072
#define NR      4
#define NC      1280   // [root | W0..W3] * 256
#define SLOTS   96

typedef __attribute__((ext_vector_type(8))) short bf16x8;
typedef __attribute__((ext_vector_type(4))) float f32x4;

__device__ __forceinline__ float sigmoidf_(float x) {
  return 1.0f / (1.0f + __expf(-x));
}

__device__ __forceinline__ ushort f2b(float v) {
  __hip_bfloat16 h = __float2bfloat16(v);
  return *(ushort*)&h;
}
__device__ __forceinline__ float b2f(ushort u) {
  __hip_bfloat16 h = *(__hip_bfloat16*)&u;
  return __bfloat162float(h);
}
__device__ __forceinline__ void split2(float v, ushort& hi, ushort& lo) {
  hi = f2b(v);
  lo = f2b(v - b2f(hi));
}

// ---------------- embedding concat -> x_hi (N,384) bf16 ----------------
__global__ void k_embed(const int* __restrict__ xi,
                        const float* __restrict__ e0, const float* __restrict__ e1,
                        const float* __restrict__ e2, const float* __restrict__ e3,
                        const float* __restrict__ e4, const float* __restrict__ e5,
                        ushort* __restrict__ xhi) {
  int n = blockIdx.x;
  int c = threadIdx.x;            // 0..383
  int i = c >> 6, d = c & 63;
  const float* t;
  switch (i) {
    case 0: t = e0; break; case 1: t = e1; break; case 2: t = e2; break;
    case 3: t = e3; break; case 4: t = e4; break; default: t = e5; break;
  }
  float v = t[(size_t)xi[n * 6 + i] * 64 + d];
  xhi[(size_t)n * 384 + c] = f2b(v);
}

// ---- fused coalesced pack: [root|W] -> Bt[n][k], LDS 64x64 transpose tiles ----
__global__ __launch_bounds__(256) void k_pack_all(
    const float* __restrict__ r1, const float* __restrict__ W1,
    const float* __restrict__ r2, const float* __restrict__ W2,
    ushort* __restrict__ B1t, ushort* __restrict__ B2thi, ushort* __restrict__ B2tlo) {
  __shared__ ushort sh[64][66];
  __shared__ ushort sl[64][66];
  int b = blockIdx.x;
  int layer, K, kt, nt, seg;
  const float *srcR, *srcW;
  if (b < 120) { layer = 1; K = 384; int t = b;       seg = t / 24; t %= 24; kt = t / 4; nt = t % 4; srcR = r1; srcW = W1; }
  else         { layer = 2; K = 256; int t = b - 120; seg = t / 16; t %= 16; kt = t / 4; nt = t % 4; srcR = r2; srcW = W2; }
  int k0 = kt * 64, n0 = nt * 64;
  int tid = threadIdx.x;
#pragma unroll
  for (int it = 0; it < 16; ++it) {
    int idx = it * 256 + tid;
    int kl = idx >> 6, nl = idx & 63;
    int kg = k0 + kl, c = n0 + nl;
    float v = (seg == 0) ? srcR[(size_t)kg * 256 + c]
                         : srcW[((size_t)(seg - 1) * K + kg) * 256 + c];
    ushort h, l; split2(v, h, l);
    sh[kl][nl] = h;
    sl[kl][nl] = l;
  }
  __syncthreads();
#pragma unroll
  for (int it = 0; it < 16; ++it) {
    int idx = it * 256 + tid;
    int nl = idx >> 6, kl = idx & 63;
    size_t o = (size_t)(seg * 256 + n0 + nl) * K + k0 + kl;
    if (layer == 1) {
      B1t[o] = sh[kl][nl];
    } else {
      B2thi[o] = sh[kl][nl];
      B2tlo[o] = sl[kl][nl];
    }
  }
}

// ------- adjacency slots + A scatter fused (A must be pre-zeroed) -------
__global__ void k_fill_scatter(const int* __restrict__ src, const int* __restrict__ dst,
                               const int* __restrict__ et,
                               int* __restrict__ cnt, int* __restrict__ slots,
                               float* __restrict__ A) {
  int e = blockIdx.x * 256 + threadIdx.x;
  if (e < NE) {
    int d = dst[e], s = src[e];
    int pos = atomicAdd(&cnt[d], 1);
    if (pos < SLOTS) slots[(size_t)d * SLOTS + pos] = (s << 2) | et[e];
    A[(size_t)s * N_NODES + d] = 1.0f;
  }
}

// ============ unified MFMA GEMM: C(M,Nc) = A(M,K) @ B(Nc,K)^T ============
// 128x128 C-tile, 4 waves. B panel LDS-staged, XOR-swizzled. (r3-exact main loop)
// SPLIT3: hi/lo 3-product. ACT: sigmoid. SYM: triangular grid + LDS-transposed mirror.
// OUT: 0 = f32 C, 1 = bf16 C.
template<int SPLIT3, int ACT, int SYM, int OUT>
__global__ __launch_bounds__(256) void k_gemm2(
    const ushort* __restrict__ Ahi, const ushort* __restrict__ Alo,
    const ushort* __restrict__ Bhi, const ushort* __restrict__ Blo,
    void* __restrict__ Cv, int Nc, int K) {
  __shared__ ushort Bs[(SPLIT3 ? 2 : 1) * 128 * 128];
  ushort* BsH = Bs;
  ushort* BsL = Bs + 128 * 128;

  const int tid = threadIdx.x;
  const int w = tid >> 6, l = tid & 63;
  const int lrow = l & 15, lk8 = (l >> 4) * 8;

  int brow, bcol, p = 0, q = 0;
  if (SYM) {
    int b = blockIdx.x;
    q = (int)((sqrtf(8.f * (float)b + 1.f) - 1.f) * 0.5f);
    while ((q + 1) * (q + 2) / 2 <= b) ++q;
    while (q * (q + 1) / 2 > b) --q;
    p = b - q * (q + 1) / 2;          // p <= q
    brow = p * 128; bcol = q * 128;
  } else {
    brow = blockIdx.y * 128; bcol = blockIdx.x * 128;
  }

  f32x4 acc[2][8] = {};
  const size_t arow0 = (size_t)(brow + w * 32 + lrow) * K + lk8;
  const size_t arow1 = arow0 + (size_t)16 * K;

  for (int kc = 0; kc < K; kc += 128) {
    bf16x8 aH[4][2], aL[4][2];
#pragma unroll
    for (int kk = 0; kk < 4; ++kk) {
      aH[kk][0] = *(const bf16x8*)(Ahi + arow0 + kc + kk * 32);
      aH[kk][1] = *(const bf16x8*)(Ahi + arow1 + kc + kk * 32);
      if (SPLIT3) {
        aL[kk][0] = *(const bf16x8*)(Alo + arow0 + kc + kk * 32);
        aL[kk][1] = *(const bf16x8*)(Alo + arow1 + kc + kk * 32);
      }
    }
    if (kc) __syncthreads();
#pragma unroll
    for (int it = 0; it < 8; ++it) {
      int o = (it * 256 + tid) * 16;
      int row = o >> 8, sb = o & 255;
      int se = (sb ^ ((row & 7) << 4)) >> 1;
      size_t g = (size_t)(bcol + row) * K + kc + se;
      *(uint4*)((char*)BsH + o) = *(const uint4*)(Bhi + g);
      if (SPLIT3) *(uint4*)((char*)BsL + o) = *(const uint4*)(Blo + g);
    }
    __syncthreads();
#pragma unroll
    for (int kk = 0; kk < 4; ++kk) {
#pragma unroll
      for (int n = 0; n < 8; ++n) {
        int row_t = n * 16 + lrow;
        int addr = row_t * 256 + ((kk * 64 + (l >> 4) * 16) ^ ((row_t & 7) << 4));
        bf16x8 b_h = *(const bf16x8*)((const char*)BsH + addr);
        acc[0][n] = __builtin_amdgcn_mfma_f32_16x16x32_bf16(aH[kk][0], b_h, acc[0][n], 0, 0, 0);
        acc[1][n] = __builtin_amdgcn_mfma_f32_16x16x32_bf16(aH[kk][1], b_h, acc[1][n], 0, 0, 0);
        if (SPLIT3) {
          bf16x8 b_l = *(const bf16x8*)((const char*)BsL + addr);
          acc[0][n] = __builtin_amdgcn_mfma_f32_16x16x32_bf16(aL[kk][0], b_h, acc[0][n], 0, 0, 0);
          acc[1][n] = __builtin_amdgcn_mfma_f32_16x16x32_bf16(aL[kk][1], b_h, acc[1][n], 0, 0, 0);
          acc[0][n] = __builtin_amdgcn_mfma_f32_16x16x32_bf16(aH[kk][0], b_l, acc[0][n], 0, 0, 0);
          acc[1][n] = __builtin_amdgcn_mfma_f32_16x16x32_bf16(aH[kk][1], b_l, acc[1][n], 0, 0, 0);
        }
      }
    }
  }

  const int crow = (l >> 4) * 4, ccol = l & 15;
  float*  Cf = (float*)Cv;
  ushort* Cb = (ushort*)Cv;
  const int domirror = (SYM && p != q);
  if (SYM) { if (domirror) __syncthreads(); }   // Bs free for reuse as transpose buffer
  float* T = (float*)Bs;                        // 128x128 f32 (64 KB) when SPLIT3
#pragma unroll
  for (int m = 0; m < 2; ++m)
#pragma unroll
    for (int n = 0; n < 8; ++n) {
      float v[4];
#pragma unroll
      for (int r = 0; r < 4; ++r) {
        float t = acc[m][n][r];
        v[r] = ACT ? sigmoidf_(t) : t;
      }
      int rloc = w * 32 + m * 16 + crow;
      int cloc = n * 16 + ccol;
#pragma unroll
      for (int r = 0; r < 4; ++r) {
        if (OUT) Cb[(size_t)(brow + rloc + r) * Nc + bcol + cloc] = f2b(v[r]);
        else     Cf[(size_t)(brow + rloc + r) * Nc + bcol + cloc] = v[r];
      }
      if (SYM && p != q) {
        int s = (cloc & 7) << 2;                // XOR swizzle on col, 4-float granule
#pragma unroll
        for (int r = 0; r < 4; ++r) T[cloc * 128 + ((rloc + r) ^ s)] = v[r];
      }
    }
  if (SYM && p != q) {
    __syncthreads();
#pragma unroll
    for (int it = 0; it < 16; ++it) {
      int idx = it * 256 + tid;
      int rw = idx >> 5;                        // 0..127 mirror row
      int c4 = (idx & 31) * 4;                  // 0..124 col chunk
      int s = (rw & 7) << 2;
      float4 val = *(const float4*)&T[rw * 128 + (c4 ^ s)];
      *(float4*)(Cf + (size_t)(bcol + rw) * Nc + brow + c4) = val;
    }
  }
}

// ---------------- threefry (partitionable) -> normal ----------------
__device__ __forceinline__ float bits_to_normal(unsigned bits) {
  float f = __uint_as_float((bits >> 9) | 0x3f800000u) - 1.0f;  // [0,1)
  const float lo = -0.99999994f;  // nextafter(-1,0) f32
  float u = __fadd_rn(__fmul_rn(f, 2.0f), lo);
  u = fmaxf(lo, u);
  float w = -log1pf(-u * u);
  float p;
  if (w < 5.0f) {
    w = w - 2.5f;
    p = 2.81022636e-08f;
    p = fmaf(p, w, 3.43273939e-07f);
    p = fmaf(p, w, -3.5233877e-06f);
    p = fmaf(p, w, -4.39150654e-06f);
    p = fmaf(p, w, 0.00021858087f);
    p = fmaf(p, w, -0.00125372503f);
    p = fmaf(p, w, -0.00417768164f);
    p = fmaf(p, w, 0.246640727f);
    p = fmaf(p, w, 1.50140941f);
  } else {
    w = sqrtf(w) - 3.0f;
    p = -0.000200214257f;
    p = fmaf(p, w, 0.000100950558f);
    p = fmaf(p, w, 0.00134934322f);
    p = fmaf(p, w, -0.00367342844f);
    p = fmaf(p, w, 0.00573950773f);
    p = fmaf(p, w, -0.0076224613f);
    p = fmaf(p, w, 0.00943887047f);
    p = fmaf(p, w, 1.00167406f);
    p = fmaf(p, w, 2.83297682f);
  }
  return 1.41421356f * (p * u);   // sqrt(2) * erfinv(u)
}

__device__ __forceinline__ unsigned threefry_bits(unsigned j) {
  const unsigned ks0 = 0u, ks1 = 42u, ks2 = 0x1BD11BDAu ^ 0u ^ 42u;
  unsigned x0 = 0u + ks0;
  unsigned x1 = j + ks1;
#define RND(r) { x0 += x1; x1 = (x1 << r) | (x1 >> (32 - r)); x1 ^= x0; }
  RND(13) RND(15) RND(26) RND(6)  x0 += ks1; x1 += ks2 + 1u;
  RND(17) RND(29) RND(16) RND(24) x0 += ks2; x1 += ks0 + 2u;
  RND(13) RND(15) RND(26) RND(6)  x0 += ks0; x1 += ks1 + 3u;
  RND(17) RND(29) RND(16) RND(24) x0 += ks1; x1 += ks2 + 4u;
  RND(13) RND(15) RND(26) RND(6)  x0 += ks2; x1 += ks0 + 5u;
#undef RND
  return x0 ^ x1;
}

// -------- combine layer 1 (bf16 hall gather) -> h1 hi/lo --------
__global__ __launch_bounds__(256) void k_combine1(
    const ushort* __restrict__ hall, const float* __restrict__ bias,
    const int* __restrict__ cnt, const int* __restrict__ slots,
    ushort* __restrict__ h_hi, ushort* __restrict__ h_lo) {
  __shared__ int sc[64];
  int n = blockIdx.x, c = threadIdx.x;
  int end = min(cnt[n], SLOTS);
  const int* sl = slots + (size_t)n * SLOTS;
  float a0 = 0.f, a1 = 0.f, a2 = 0.f, a3 = 0.f;
  int c0 = 0, c1 = 0, c2 = 0, c3 = 0;
  for (int base = 0; base < end; base += 64) {
    int mcnt = min(64, end - base);
    if (c < 64 && base + c < end) sc[c] = sl[base + c];
    __syncthreads();
    int i = 0;
    for (; i + 4 <= mcnt; i += 4) {
      int p0 = sc[i], p1 = sc[i + 1], p2 = sc[i + 2], p3 = sc[i + 3];
      float v0 = b2f(hall[(size_t)(p0 >> 2) * NC + 256 + (size_t)(p0 & 3) * 256 + c]);
      float v1 = b2f(hall[(size_t)(p1 >> 2) * NC + 256 + (size_t)(p1 & 3) * 256 + c]);
      float v2 = b2f(hall[(size_t)(p2 >> 2) * NC + 256 + (size_t)(p2 & 3) * 256 + c]);
      float v3 = b2f(hall[(size_t)(p3 >> 2) * NC + 256 + (size_t)(p3 & 3) * 256 + c]);
      int r;
      r = p0 & 3; if (r == 0) { a0 += v0; ++c0; } else if (r == 1) { a1 += v0; ++c1; }
                  else if (r == 2) { a2 += v0; ++c2; } else { a3 += v0; ++c3; }
      r = p1 & 3; if (r == 0) { a0 += v1; ++c0; } else if (r == 1) { a1 += v1; ++c1; }
                  else if (r == 2) { a2 += v1; ++c2; } else { a3 += v1; ++c3; }
      r = p2 & 3; if (r == 0) { a0 += v2; ++c0; } else if (r == 1) { a1 += v2; ++c1; }
                  else if (r == 2) { a2 += v2; ++c2; } else { a3 += v2; ++c3; }
      r = p3 & 3; if (r == 0) { a0 += v3; ++c0; } else if (r == 1) { a1 += v3; ++c1; }
                  else if (r == 2) { a2 += v3; ++c2; } else { a3 += v3; ++c3; }
    }
    for (; i < mcnt; ++i) {
      int pp = sc[i];
      int r = pp & 3;
      float v = b2f(hall[(size_t)(pp >> 2) * NC + 256 + (size_t)r * 256 + c]);
      if (r == 0) { a0 += v; ++c0; } else if (r == 1) { a1 += v; ++c1; }
      else if (r == 2) { a2 += v; ++c2; } else { a3 += v; ++c3; }
    }
    __syncthreads();
  }
  float v = b2f(hall[(size_t)n * NC + c]) + bias[c]
          + a0 / (float)max(c0, 1) + a1 / (float)max(c1, 1)
          + a2 / (float)max(c2, 1) + a3 / (float)max(c3, 1);
  float sg = sigmoidf_(v);
  ushort h, l; split2(sg, h, l);
  h_hi[(size_t)n * 256 + c] = h;
  h_lo[(size_t)n * 256 + c] = l;
}

// -------- combine layer 2 (f32 hall) + fused reparametrize --------
__global__ __launch_bounds__(256) void k_combine2z(
    const float* __restrict__ hall, const float* __restrict__ bias,
    const int* __restrict__ cnt, const int* __restrict__ slots,
    float* __restrict__ muo, float* __restrict__ lvo,
    ushort* __restrict__ zhi, ushort* __restrict__ zlo) {
  __shared__ int sc[64];
  __shared__ float sv[256];
  int n = blockIdx.x, c = threadIdx.x;
  int end = min(cnt[n], SLOTS);
  const int* sl = slots + (size_t)n * SLOTS;
  float a0 = 0.f, a1 = 0.f, a2 = 0.f, a3 = 0.f;
  int c0 = 0, c1 = 0, c2 = 0, c3 = 0;
  for (int base = 0; base < end; base += 64) {
    int mcnt = min(64, end - base);
    if (c < 64 && base + c < end) sc[c] = sl[base + c];
    __syncthreads();
    int i = 0;
    for (; i + 4 <= mcnt; i += 4) {
      int p0 = sc[i], p1 = sc[i + 1], p2 = sc[i + 2], p3 = sc[i + 3];
      float v0 = hall[(size_t)(p0 >> 2) * NC + 256 + (size_t)(p0 & 3) * 256 + c];
      float v1 = hall[(size_t)(p1 >> 2) * NC + 256 + (size_t)(p1 & 3) * 256 + c];
      float v2 = hall[(size_t)(p2 >> 2) * NC + 256 + (size_t)(p2 & 3) * 256 + c];
      float v3 = hall[(size_t)(p3 >> 2) * NC + 256 + (size_t)(p3 & 3) * 256 + c];
      int r;
      r = p0 & 3; if (r == 0) { a0 += v0; ++c0; } else if (r == 1) { a1 += v0; ++c1; }
                  else if (r == 2) { a2 += v0; ++c2; } else { a3 += v0; ++c3; }
      r = p1 & 3; if (r == 0) { a0 += v1; ++c0; } else if (r == 1) { a1 += v1; ++c1; }
                  else if (r == 2) { a2 += v1; ++c2; } else { a3 += v1; ++c3; }
      r = p2 & 3; if (r == 0) { a0 += v2; ++c0; } else if (r == 1) { a1 += v2; ++c1; }
                  else if (r == 2) { a2 += v2; ++c2; } else { a3 += v2; ++c3; }
      r = p3 & 3; if (r == 0) { a0 += v3; ++c0; } else if (r == 1) { a1 += v3; ++c1; }
                  else if (r == 2) { a2 += v3; ++c2; } else { a3 += v3; ++c3; }
    }
    for (; i < mcnt; ++i) {
      int pp = sc[i];
      int r = pp & 3;
      float v = hall[(size_t)(pp >> 2) * NC + 256 + (size_t)r * 256 + c];
      if (r == 0) { a0 += v; ++c0; } else if (r == 1) { a1 += v; ++c1; }
      else if (r == 2) { a2 += v; ++c2; } else { a3 += v; ++c3; }
    }
    __syncthreads();
  }
  float v = hall[(size_t)n * NC + c] + bias[c]
          + a0 / (float)max(c0, 1) + a1 / (float)max(c1, 1)
          + a2 / (float)max(c2, 1) + a3 / (float)max(c3, 1);
  float sg = sigmoidf_(v);
  if (c < 128) muo[(size_t)n * 128 + c] = sg;
  else         lvo[(size_t)n * 128 + (c - 128)] = sg;
  sv[c] = sg;
  __syncthreads();
  if (c < 128) {
    unsigned j = (unsigned)n * 128u + (unsigned)c;
    float e = bits_to_normal(threefry_bits(j));
    float z = fmaf(e, __expf(0.5f * sv[c + 128]), sv[c]);
    ushort h, l; split2(z, h, l);
    zhi[j] = h; zlo[j] = l;
  }
}

// ---------------- zero helper ----------------
__global__ void k_zerof4(float4* __restrict__ p, size_t n4) {
  size_t i = (size_t)blockIdx.x * blockDim.x + threadIdx.x;
  size_t stride = (size_t)gridDim.x * blockDim.x;
  float4 z = make_float4(0.f, 0.f, 0.f, 0.f);
  for (; i < n4; i += stride) p[i] = z;
}

extern "C" void kernel_launch(void* const* d_in, const int* in_sizes, int n_in,
                              void* d_out, int out_size, void* d_ws, size_t ws_size,
                              hipStream_t stream) {
  const int* x    = (const int*)d_in[0];
  const int* ei   = (const int*)d_in[1];
  const int* src  = ei;
  const int* dst  = ei + NE;
  const int* et   = (const int*)d_in[2];
  const float* e0 = (const float*)d_in[3];
  const float* e1 = (const float*)d_in[4];
  const float* e2 = (const float*)d_in[5];
  const float* e3 = (const float*)d_in[6];
  const float* e4 = (const float*)d_in[7];
  const float* e5 = (const float*)d_in[8];
  const float* W1 = (const float*)d_in[9];
  const float* r1 = (const float*)d_in[10];
  const float* b1 = (const float*)d_in[11];
  const float* W2 = (const float*)d_in[12];
  const float* r2 = (const float*)d_in[13];
  const float* b2 = (const float*)d_in[14];

  float* out  = (float*)d_out;
  float* A    = out;                                    // N*N
  float* Ahat = out + (size_t)N_NODES * N_NODES;        // N*N
  float* muo  = Ahat + (size_t)N_NODES * N_NODES;       // N*128
  float* lvo  = muo + (size_t)N_NODES * 128;            // N*128

  char* wp = (char*)d_ws;
  auto carve = [&](size_t bytes) { char* r = wp; wp += (bytes + 255) & ~(size_t)255; return r; };
  ushort* B1t    = (ushort*)carve((size_t)NC * 384 * 2);
  ushort* B2thi  = (ushort*)carve((size_t)NC * 256 * 2);
  ushort* B2tlo  = (ushort*)carve((size_t)NC * 256 * 2);
  float*  hall   = (float*)carve((size_t)8192 * NC * 4);  // f32 layer2; bf16 alias layer1
  ushort* hallb  = (ushort*)hall;
  ushort* h1hi   = (ushort*)carve((size_t)8192 * 256 * 2);
  ushort* h1lo   = (ushort*)carve((size_t)8192 * 256 * 2);
  ushort* zhi    = (ushort*)carve((size_t)8192 * 128 * 2);
  ushort* zlo    = (ushort*)carve((size_t)8192 * 128 * 2);
  int*    cnt    = (int*)carve((size_t)8192 * 4);
  int*    slots  = (int*)carve((size_t)8192 * SLOTS * 4);
  ushort* xhi    = (ushort*)carve((size_t)8192 * 384 * 2);

  // ---- A zeroed first; then adjacency slots + A scatter in one edge pass ----
  k_zerof4<<<8192, 256, 0, stream>>>((float4*)A, (size_t)N_NODES * N_NODES / 4);
  hipMemsetAsync(cnt, 0, (size_t)8192 * 4, stream);
  k_fill_scatter<<<NE / 256, 256, 0, stream>>>(src, dst, et, cnt, slots, A);

  // ---- preprocessing ----
  k_embed<<<8192, 384, 0, stream>>>(x, e0, e1, e2, e3, e4, e5, xhi);
  k_pack_all<<<200, 256, 0, stream>>>(r1, W1, r2, W2, B1t, B2thi, B2tlo);

  // ---- layer 1 (hi-only GEMM, bf16 hall) ----
  k_gemm2<0, 0, 0, 1><<<dim3(NC / 128, 64), 256, 0, stream>>>(
      xhi, nullptr, B1t, nullptr, hallb, NC, 384);
  k_combine1<<<8192, 256, 0, stream>>>(hallb, b1, cnt, slots, h1hi, h1lo);

  // ---- layer 2 (split-3 GEMM, f32 hall) + fused reparametrize ----
  k_gemm2<1, 0, 0, 0><<<dim3(NC / 128, 64), 256, 0, stream>>>(
      h1hi, h1lo, B2thi, B2tlo, hall, NC, 256);
  k_combine2z<<<8192, 256, 0, stream>>>(hall, b2, cnt, slots, muo, lvo, zhi, zlo);

  // ---- A_hat = sigmoid(Z @ Z^T): sym triangle, LDS-transposed mirror writes ----
  k_gemm2<1, 1, 1, 0><<<dim3(64 * 65 / 2), 256, 0, stream>>>(
      zhi, zlo, zhi, zlo, Ahat, N_NODES, 128);
}

// Round 11
// 289.195 us; speedup vs baseline: 1.0912x; 1.0063x over previous
//
#include <hip/hip_runtime.h>
#include <hip/hip_bf16.h>
#include <cstdint>
#include <cstddef>

#define N_NODES 8192
#define NE      131072
#define NR      4
#define NC      1280   // [root | W0..W3] * 256
#define SLOTS   96

typedef __attribute__((ext_vector_type(8))) short bf16x8;
typedef __attribute__((ext_vector_type(4))) float f32x4;

__device__ __forceinline__ float sigmoidf_(float x) {
  return 1.0f / (1.0f + __expf(-x));
}

__device__ __forceinline__ ushort f2b(float v) {
  __hip_bfloat16 h = __float2bfloat16(v);
  return *(ushort*)&h;
}
__device__ __forceinline__ float b2f(ushort u) {
  __hip_bfloat16 h = *(__hip_bfloat16*)&u;
  return __bfloat162float(h);
}
__device__ __forceinline__ void split2(float v, ushort& hi, ushort& lo) {
  hi = f2b(v);
  lo = f2b(v - b2f(hi));
}

// ---------------- embedding concat -> x_hi (N,384) bf16 ----------------
__global__ void k_embed(const int* __restrict__ xi,
                        const float* __restrict__ e0, const float* __restrict__ e1,
                        const float* __restrict__ e2, const float* __restrict__ e3,
                        const float* __restrict__ e4, const float* __restrict__ e5,
                        ushort* __restrict__ xhi) {
  int n = blockIdx.x;
  int c = threadIdx.x;            // 0..383
  int i = c >> 6, d = c & 63;
  const float* t;
  switch (i) {
    case 0: t = e0; break; case 1: t = e1; break; case 2: t = e2; break;
    case 3: t = e3; break; case 4: t = e4; break; default: t = e5; break;
  }
  float v = t[(size_t)xi[n * 6 + i] * 64 + d];
  xhi[(size_t)n * 384 + c] = f2b(v);
}

// ---- fused coalesced pack: [root|W] -> Bt[n][k], LDS 64x64 transpose tiles ----
__global__ __launch_bounds__(256) void k_pack_all(
    const float* __restrict__ r1, const float* __restrict__ W1,
    const float* __restrict__ r2, const float* __restrict__ W2,
    ushort* __restrict__ B1t, ushort* __restrict__ B2thi, ushort* __restrict__ B2tlo) {
  __shared__ ushort sh[64][66];
  __shared__ ushort sl[64][66];
  int b = blockIdx.x;
  int layer, K, kt, nt, seg;
  const float *srcR, *srcW;
  if (b < 120) { layer = 1; K = 384; int t = b;       seg = t / 24; t %= 24; kt = t / 4; nt = t % 4; srcR = r1; srcW = W1; }
  else         { layer = 2; K = 256; int t = b - 120; seg = t / 16; t %= 16; kt = t / 4; nt = t % 4; srcR = r2; srcW = W2; }
  int k0 = kt * 64, n0 = nt * 64;
  int tid = threadIdx.x;
#pragma unroll
  for (int it = 0; it < 16; ++it) {
    int idx = it * 256 + tid;
    int kl = idx >> 6, nl = idx & 63;
    int kg = k0 + kl, c = n0 + nl;
    float v = (seg == 0) ? srcR[(size_t)kg * 256 + c]
                         : srcW[((size_t)(seg - 1) * K + kg) * 256 + c];
    ushort h, l; split2(v, h, l);
    sh[kl][nl] = h;
    sl[kl][nl] = l;
  }
  __syncthreads();
#pragma unroll
  for (int it = 0; it < 16; ++it) {
    int idx = it * 256 + tid;
    int nl = idx >> 6, kl = idx & 63;
    size_t o = (size_t)(seg * 256 + n0 + nl) * K + k0 + kl;
    if (layer == 1) {
      B1t[o] = sh[kl][nl];
    } else {
      B2thi[o] = sh[kl][nl];
      B2tlo[o] = sl[kl][nl];
    }
  }
}

// ------- adjacency slots + A scatter fused (A must be pre-zeroed) -------
__global__ void k_fill_scatter(const int* __restrict__ src, const int* __restrict__ dst,
                               const int* __restrict__ et,
                               int* __restrict__ cnt, int* __restrict__ slots,
                               float* __restrict__ A) {
  int e = blockIdx.x * 256 + threadIdx.x;
  if (e < NE) {
    int d = dst[e], s = src[e];
    int pos = atomicAdd(&cnt[d], 1);
    if (pos < SLOTS) slots[(size_t)d * SLOTS + pos] = (s << 2) | et[e];
    A[(size_t)s * N_NODES + d] = 1.0f;
  }
}

// ============ unified MFMA GEMM: C(M,Nc) = A(M,K) @ B(Nc,K)^T ============
// 128x128 C-tile, 4 waves. B panel LDS-staged, XOR-swizzled. (r3-exact main loop)
// SPLIT3: hi/lo 3-product. ACT: sigmoid. SYM: triangular grid + LDS-transposed mirror.
// OUT: 0 = f32 C, 1 = bf16 C.
template<int SPLIT3, int ACT, int SYM, int OUT>
__global__ __launch_bounds__(256) void k_gemm2(
    const ushort* __restrict__ Ahi, const ushort* __restrict__ Alo,
    const ushort* __restrict__ Bhi, const ushort* __restrict__ Blo,
    void* __restrict__ Cv, int Nc, int K) {
  __shared__ ushort Bs[(SPLIT3 ? 2 : 1) * 128 * 128];
  ushort* BsH = Bs;
  ushort* BsL = Bs + 128 * 128;

  const int tid = threadIdx.x;
  const int w = tid >> 6, l = tid & 63;
  const int lrow = l & 15, lk8 = (l >> 4) * 8;

  int brow, bcol, p = 0, q = 0;
  if (SYM) {
    int b = blockIdx.x;
    q = (int)((sqrtf(8.f * (float)b + 1.f) - 1.f) * 0.5f);
    while ((q + 1) * (q + 2) / 2 <= b) ++q;
    while (q * (q + 1) / 2 > b) --q;
    p = b - q * (q + 1) / 2;          // p <= q
    brow = p * 128; bcol = q * 128;
  } else {
    brow = blockIdx.y * 128; bcol = blockIdx.x * 128;
  }

  f32x4 acc[2][8] = {};
  const size_t arow0 = (size_t)(brow + w * 32 + lrow) * K + lk8;
  const size_t arow1 = arow0 + (size_t)16 * K;

  for (int kc = 0; kc < K; kc += 128) {
    bf16x8 aH[4][2], aL[4][2];
#pragma unroll
    for (int kk = 0; kk < 4; ++kk) {
      aH[kk][0] = *(const bf16x8*)(Ahi + arow0 + kc + kk * 32);
      aH[kk][1] = *(const bf16x8*)(Ahi + arow1 + kc + kk * 32);
      if (SPLIT3) {
        aL[kk][0] = *(const bf16x8*)(Alo + arow0 + kc + kk * 32);
        aL[kk][1] = *(const bf16x8*)(Alo + arow1 + kc + kk * 32);
      }
    }
    if (kc) __syncthreads();
#pragma unroll
    for (int it = 0; it < 8; ++it) {
      int o = (it * 256 + tid) * 16;
      int row = o >> 8, sb = o & 255;
      int se = (sb ^ ((row & 7) << 4)) >> 1;
      size_t g = (size_t)(bcol + row) * K + kc + se;
      *(uint4*)((char*)BsH + o) = *(const uint4*)(Bhi + g);
      if (SPLIT3) *(uint4*)((char*)BsL + o) = *(const uint4*)(Blo + g);
    }
    __syncthreads();
#pragma unroll
    for (int kk = 0; kk < 4; ++kk) {
#pragma unroll
      for (int n = 0; n < 8; ++n) {
        int row_t = n * 16 + lrow;
        int addr = row_t * 256 + ((kk * 64 + (l >> 4) * 16) ^ ((row_t & 7) << 4));
        bf16x8 b_h = *(const bf16x8*)((const char*)BsH + addr);
        acc[0][n] = __builtin_amdgcn_mfma_f32_16x16x32_bf16(aH[kk][0], b_h, acc[0][n], 0, 0, 0);
        acc[1][n] = __builtin_amdgcn_mfma_f32_16x16x32_bf16(aH[kk][1], b_h, acc[1][n], 0, 0, 0);
        if (SPLIT3) {
          bf16x8 b_l = *(const bf16x8*)((const char*)BsL + addr);
          acc[0][n] = __builtin_amdgcn_mfma_f32_16x16x32_bf16(aL[kk][0], b_h, acc[0][n], 0, 0, 0);
          acc[1][n] = __builtin_amdgcn_mfma_f32_16x16x32_bf16(aL[kk][1], b_h, acc[1][n], 0, 0, 0);
          acc[0][n] = __builtin_amdgcn_mfma_f32_16x16x32_bf16(aH[kk][0], b_l, acc[0][n], 0, 0, 0);
          acc[1][n] = __builtin_amdgcn_mfma_f32_16x16x32_bf16(aH[kk][1], b_l, acc[1][n], 0, 0, 0);
        }
      }
    }
  }

  const int crow = (l >> 4) * 4, ccol = l & 15;
  float*  Cf = (float*)Cv;
  ushort* Cb = (ushort*)Cv;
  const int domirror = (SYM && p != q);
  if (SYM) { if (domirror) __syncthreads(); }   // Bs free for reuse as transpose buffer
  float* T = (float*)Bs;                        // 128x128 f32 (64 KB) when SPLIT3
#pragma unroll
  for (int m = 0; m < 2; ++m)
#pragma unroll
    for (int n = 0; n < 8; ++n) {
      float v[4];
#pragma unroll
      for (int r = 0; r < 4; ++r) {
        float t = acc[m][n][r];
        v[r] = ACT ? sigmoidf_(t) : t;
      }
      int rloc = w * 32 + m * 16 + crow;
      int cloc = n * 16 + ccol;
#pragma unroll
      for (int r = 0; r < 4; ++r) {
        if (OUT) Cb[(size_t)(brow + rloc + r) * Nc + bcol + cloc] = f2b(v[r]);
        else     Cf[(size_t)(brow + rloc + r) * Nc + bcol + cloc] = v[r];
      }
      if (SYM && p != q) {
        int s = (cloc & 7) << 2;                // XOR swizzle on col, 4-float granule
#pragma unroll
        for (int r = 0; r < 4; ++r) T[cloc * 128 + ((rloc + r) ^ s)] = v[r];
      }
    }
  if (SYM && p != q) {
    __syncthreads();
#pragma unroll
    for (int it = 0; it < 16; ++it) {
      int idx = it * 256 + tid;
      int rw = idx >> 5;                        // 0..127 mirror row
      int c4 = (idx & 31) * 4;                  // 0..124 col chunk
      int s = (rw & 7) << 2;
      float4 val = *(const float4*)&T[rw * 128 + (c4 ^ s)];
      *(float4*)(Cf + (size_t)(bcol + rw) * Nc + brow + c4) = val;
    }
  }
}

// ---------------- threefry (partitionable) -> normal ----------------
__device__ __forceinline__ float bits_to_normal(unsigned bits) {
  float f = __uint_as_float((bits >> 9) | 0x3f800000u) - 1.0f;  // [0,1)
  const float lo = -0.99999994f;  // nextafter(-1,0) f32
  float u = __fadd_rn(__fmul_rn(f, 2.0f), lo);
  u = fmaxf(lo, u);
  float w = -log1pf(-u * u);
  float p;
  if (w < 5.0f) {
    w = w - 2.5f;
    p = 2.81022636e-08f;
    p = fmaf(p, w, 3.43273939e-07f);
    p = fmaf(p, w, -3.5233877e-06f);
    p = fmaf(p, w, -4.39150654e-06f);
    p = fmaf(p, w, 0.00021858087f);
    p = fmaf(p, w, -0.00125372503f);
    p = fmaf(p, w, -0.00417768164f);
    p = fmaf(p, w, 0.246640727f);
    p = fmaf(p, w, 1.50140941f);
  } else {
    w = sqrtf(w) - 3.0f;
    p = -0.000200214257f;
    p = fmaf(p, w, 0.000100950558f);
    p = fmaf(p, w, 0.00134934322f);
    p = fmaf(p, w, -0.00367342844f);
    p = fmaf(p, w, 0.00573950773f);
    p = fmaf(p, w, -0.0076224613f);
    p = fmaf(p, w, 0.00943887047f);
    p = fmaf(p, w, 1.00167406f);
    p = fmaf(p, w, 2.83297682f);
  }
  return 1.41421356f * (p * u);   // sqrt(2) * erfinv(u)
}

__device__ __forceinline__ unsigned threefry_bits(unsigned j) {
  const unsigned ks0 = 0u, ks1 = 42u, ks2 = 0x1BD11BDAu ^ 0u ^ 42u;
  unsigned x0 = 0u + ks0;
  unsigned x1 = j + ks1;
#define RND(r) { x0 += x1; x1 = (x1 << r) | (x1 >> (32 - r)); x1 ^= x0; }
  RND(13) RND(15) RND(26) RND(6)  x0 += ks1; x1 += ks2 + 1u;
  RND(17) RND(29) RND(16) RND(24) x0 += ks2; x1 += ks0 + 2u;
  RND(13) RND(15) RND(26) RND(6)  x0 += ks0; x1 += ks1 + 3u;
  RND(17) RND(29) RND(16) RND(24) x0 += ks1; x1 += ks2 + 4u;
  RND(13) RND(15) RND(26) RND(6)  x0 += ks2; x1 += ks0 + 5u;
#undef RND
  return x0 ^ x1;
}

// -------- combine layer 1 (bf16 hall gather) -> h1 hi/lo --------
__global__ __launch_bounds__(256) void k_combine1(
    const ushort* __restrict__ hall, const float* __restrict__ bias,
    const int* __restrict__ cnt, const int* __restrict__ slots,
    ushort* __restrict__ h_hi, ushort* __restrict__ h_lo) {
  __shared__ int sc[64];
  int n = blockIdx.x, c = threadIdx.x;
  int end = min(cnt[n], SLOTS);
  const int* sl = slots + (size_t)n * SLOTS;
  float a0 = 0.f, a1 = 0.f, a2 = 0.f, a3 = 0.f;
  int c0 = 0, c1 = 0, c2 = 0, c3 = 0;
  for (int base = 0; base < end; base += 64) {
    int mcnt = min(64, end - base);
    if (c < 64 && base + c < end) sc[c] = sl[base + c];
    __syncthreads();
    int i = 0;
    for (; i + 4 <= mcnt; i += 4) {
      int p0 = sc[i], p1 = sc[i + 1], p2 = sc[i + 2], p3 = sc[i + 3];
      float v0 = b2f(hall[(size_t)(p0 >> 2) * NC + 256 + (size_t)(p0 & 3) * 256 + c]);
      float v1 = b2f(hall[(size_t)(p1 >> 2) * NC + 256 + (size_t)(p1 & 3) * 256 + c]);
      float v2 = b2f(hall[(size_t)(p2 >> 2) * NC + 256 + (size_t)(p2 & 3) * 256 + c]);
      float v3 = b2f(hall[(size_t)(p3 >> 2) * NC + 256 + (size_t)(p3 & 3) * 256 + c]);
      int r;
      r = p0 & 3; if (r == 0) { a0 += v0; ++c0; } else if (r == 1) { a1 += v0; ++c1; }
                  else if (r == 2) { a2 += v0; ++c2; } else { a3 += v0; ++c3; }
      r = p1 & 3; if (r == 0) { a0 += v1; ++c0; } else if (r == 1) { a1 += v1; ++c1; }
                  else if (r == 2) { a2 += v1; ++c2; } else { a3 += v1; ++c3; }
      r = p2 & 3; if (r == 0) { a0 += v2; ++c0; } else if (r == 1) { a1 += v2; ++c1; }
                  else if (r == 2) { a2 += v2; ++c2; } else { a3 += v2; ++c3; }
      r = p3 & 3; if (r == 0) { a0 += v3; ++c0; } else if (r == 1) { a1 += v3; ++c1; }
                  else if (r == 2) { a2 += v3; ++c2; } else { a3 += v3; ++c3; }
    }
    for (; i < mcnt; ++i) {
      int pp = sc[i];
      int r = pp & 3;
      float v = b2f(hall[(size_t)(pp >> 2) * NC + 256 + (size_t)r * 256 + c]);
      if (r == 0) { a0 += v; ++c0; } else if (r == 1) { a1 += v; ++c1; }
      else if (r == 2) { a2 += v; ++c2; } else { a3 += v; ++c3; }
    }
    __syncthreads();
  }
  float v = b2f(hall[(size_t)n * NC + c]) + bias[c]
          + a0 / (float)max(c0, 1) + a1 / (float)max(c1, 1)
          + a2 / (float)max(c2, 1) + a3 / (float)max(c3, 1);
  float sg = sigmoidf_(v);
  ushort h, l; split2(sg, h, l);
  h_hi[(size_t)n * 256 + c] = h;
  h_lo[(size_t)n * 256 + c] = l;
}

// -------- combine layer 2 (bf16 hall gather) + fused reparametrize --------
__global__ __launch_bounds__(256) void k_combine2z(
    const ushort* __restrict__ hall, const float* __restrict__ bias,
    const int* __restrict__ cnt, const int* __restrict__ slots,
    float* __restrict__ muo, float* __restrict__ lvo,
    ushort* __restrict__ zhi, ushort* __restrict__ zlo) {
  __shared__ int sc[64];
  __shared__ float sv[256];
  int n = blockIdx.x, c = threadIdx.x;
  int end = min(cnt[n], SLOTS);
  const int* sl = slots + (size_t)n * SLOTS;
  float a0 = 0.f, a1 = 0.f, a2 = 0.f, a3 = 0.f;
  int c0 = 0, c1 = 0, c2 = 0, c3 = 0;
  for (int base = 0; base < end; base += 64) {
    int mcnt = min(64, end - base);
    if (c < 64 && base + c < end) sc[c] = sl[base + c];
    __syncthreads();
    int i = 0;
    for (; i + 4 <= mcnt; i += 4) {
      int p0 = sc[i], p1 = sc[i + 1], p2 = sc[i + 2], p3 = sc[i + 3];
      float v0 = b2f(hall[(size_t)(p0 >> 2) * NC + 256 + (size_t)(p0 & 3) * 256 + c]);
      float v1 = b2f(hall[(size_t)(p1 >> 2) * NC + 256 + (size_t)(p1 & 3) * 256 + c]);
      float v2 = b2f(hall[(size_t)(p2 >> 2) * NC + 256 + (size_t)(p2 & 3) * 256 + c]);
      float v3 = b2f(hall[(size_t)(p3 >> 2) * NC + 256 + (size_t)(p3 & 3) * 256 + c]);
      int r;
      r = p0 & 3; if (r == 0) { a0 += v0; ++c0; } else if (r == 1) { a1 += v0; ++c1; }
                  else if (r == 2) { a2 += v0; ++c2; } else { a3 += v0; ++c3; }
      r = p1 & 3; if (r == 0) { a0 += v1; ++c0; } else if (r == 1) { a1 += v1; ++c1; }
                  else if (r == 2) { a2 += v1; ++c2; } else { a3 += v1; ++c3; }
      r = p2 & 3; if (r == 0) { a0 += v2; ++c0; } else if (r == 1) { a1 += v2; ++c1; }
                  else if (r == 2) { a2 += v2; ++c2; } else { a3 += v2; ++c3; }
      r = p3 & 3; if (r == 0) { a0 += v3; ++c0; } else if (r == 1) { a1 += v3; ++c1; }
                  else if (r == 2) { a2 += v3; ++c2; } else { a3 += v3; ++c3; }
    }
    for (; i < mcnt; ++i) {
      int pp = sc[i];
      int r = pp & 3;
      float v = b2f(hall[(size_t)(pp >> 2) * NC + 256 + (size_t)r * 256 + c]);
      if (r == 0) { a0 += v; ++c0; } else if (r == 1) { a1 += v; ++c1; }
      else if (r == 2) { a2 += v; ++c2; } else { a3 += v; ++c3; }
    }
    __syncthreads();
  }
  float v = b2f(hall[(size_t)n * NC + c]) + bias[c]
          + a0 / (float)max(c0, 1) + a1 / (float)max(c1, 1)
          + a2 / (float)max(c2, 1) + a3 / (float)max(c3, 1);
  float sg = sigmoidf_(v);
  if (c < 128) muo[(size_t)n * 128 + c] = sg;
  else         lvo[(size_t)n * 128 + (c - 128)] = sg;
  sv[c] = sg;
  __syncthreads();
  if (c < 128) {
    unsigned j = (unsigned)n * 128u + (unsigned)c;
    float e = bits_to_normal(threefry_bits(j));
    float z = fmaf(e, __expf(0.5f * sv[c + 128]), sv[c]);
    ushort h, l; split2(z, h, l);
    zhi[j] = h; zlo[j] = l;
  }
}

// ---------------- zero helper ----------------
__global__ void k_zerof4(float4* __restrict__ p, size_t n4) {
  size_t i = (size_t)blockIdx.x * blockDim.x + threadIdx.x;
  size_t stride = (size_t)gridDim.x * blockDim.x;
  float4 z = make_float4(0.f, 0.f, 0.f, 0.f);
  for (; i < n4; i += stride) p[i] = z;
}

extern "C" void kernel_launch(void* const* d_in, const int* in_sizes, int n_in,
                              void* d_out, int out_size, void* d_ws, size_t ws_size,
                              hipStream_t stream) {
  const int* x    = (const int*)d_in[0];
  const int* ei   = (const int*)d_in[1];
  const int* src  = ei;
  const int* dst  = ei + NE;
  const int* et   = (const int*)d_in[2];
  const float* e0 = (const float*)d_in[3];
  const float* e1 = (const float*)d_in[4];
  const float* e2 = (const float*)d_in[5];
  const float* e3 = (const float*)d_in[6];
  const float* e4 = (const float*)d_in[7];
  const float* e5 = (const float*)d_in[8];
  const float* W1 = (const float*)d_in[9];
  const float* r1 = (const float*)d_in[10];
  const float* b1 = (const float*)d_in[11];
  const float* W2 = (const float*)d_in[12];
  const float* r2 = (const float*)d_in[13];
  const float* b2 = (const float*)d_in[14];

  float* out  = (float*)d_out;
  float* A    = out;                                    // N*N
  float* Ahat = out + (size_t)N_NODES * N_NODES;        // N*N
  float* muo  = Ahat + (size_t)N_NODES * N_NODES;       // N*128
  float* lvo  = muo + (size_t)N_NODES * 128;            // N*128

  char* wp = (char*)d_ws;
  auto carve = [&](size_t bytes) { char* r = wp; wp += (bytes + 255) & ~(size_t)255; return r; };
  ushort* B1t    = (ushort*)carve((size_t)NC * 384 * 2);
  ushort* B2thi  = (ushort*)carve((size_t)NC * 256 * 2);
  ushort* B2tlo  = (ushort*)carve((size_t)NC * 256 * 2);
  ushort* hallb  = (ushort*)carve((size_t)8192 * NC * 2);  // bf16 hall (both layers)
  ushort* h1hi   = (ushort*)carve((size_t)8192 * 256 * 2);
  ushort* h1lo   = (ushort*)carve((size_t)8192 * 256 * 2);
  ushort* zhi    = (ushort*)carve((size_t)8192 * 128 * 2);
  ushort* zlo    = (ushort*)carve((size_t)8192 * 128 * 2);
  int*    cnt    = (int*)carve((size_t)8192 * 4);
  int*    slots  = (int*)carve((size_t)8192 * SLOTS * 4);
  ushort* xhi    = (ushort*)carve((size_t)8192 * 384 * 2);

  // ---- A zeroed first; then adjacency slots + A scatter in one edge pass ----
  k_zerof4<<<8192, 256, 0, stream>>>((float4*)A, (size_t)N_NODES * N_NODES / 4);
  hipMemsetAsync(cnt, 0, (size_t)8192 * 4, stream);
  k_fill_scatter<<<NE / 256, 256, 0, stream>>>(src, dst, et, cnt, slots, A);

  // ---- preprocessing ----
  k_embed<<<8192, 384, 0, stream>>>(x, e0, e1, e2, e3, e4, e5, xhi);
  k_pack_all<<<200, 256, 0, stream>>>(r1, W1, r2, W2, B1t, B2thi, B2tlo);

  // ---- layer 1 (hi-only GEMM, bf16 hall) ----
  k_gemm2<0, 0, 0, 1><<<dim3(NC / 128, 64), 256, 0, stream>>>(
      xhi, nullptr, B1t, nullptr, hallb, NC, 384);
  k_combine1<<<8192, 256, 0, stream>>>(hallb, b1, cnt, slots, h1hi, h1lo);

  // ---- layer 2 (split-3 GEMM, bf16 hall) + fused reparametrize ----
  k_gemm2<1, 0, 0, 1><<<dim3(NC / 128, 64), 256, 0, stream>>>(
      h1hi, h1lo, B2thi, B2tlo, hallb, NC, 256);
  k_combine2z<<<8192, 256, 0, stream>>>(hallb, b2, cnt, slots, muo, lvo, zhi, zlo);

  // ---- A_hat = sigmoid(Z @ Z^T): sym triangle, LDS-transposed mirror writes ----
  k_gemm2<1, 1, 1, 0><<<dim3(64 * 65 / 2), 256, 0, stream>>>(
      zhi, zlo, zhi, zlo, Ahat, N_NODES, 128);
}